// Round 3
// baseline (9151.175 us; speedup 1.0000x reference)
//
#include <hip/hip_runtime.h>
#include <hip/hip_bf16.h>

#define VOCAB 32000
#define EMBED 512
#define ENCD  512
#define HID   1024
#define ATTN  128
#define SRC   1024
#define TGT   512

typedef __hip_bfloat16 bf16;
typedef __attribute__((ext_vector_type(8))) short bf16x8v;
typedef __attribute__((ext_vector_type(4))) float f32x4;

// ---- workspace layout (float offsets), total 13.8 MB ----
#define OFF_ENCPROJ 0                         // [1024][128]
#define OFF_WAHT    (131072)                  // [1024][128]  Wa_h transposed
#define OFF_G       (262144)                  // [512][4096]  emb-part of gates + biases
#define OFF_HH      (2359296)                 // [513][1024]  h history (row0 = initial_h)
#define OFF_CC      (2884608)                 // [1024]       c state
#define OFF_P       (2885632)                 // [512][1024]  unnormalized attn
#define OFF_INVDEN  (3409920)                 // [512]
#define OFF_CTXP    (3410432)                 // [32][512]    ctx partials
#define OFF_DENP    (3426816)                 // [32]
#define OFF_WAHP    (3426848)                 // [128][128]   wah partials

__device__ __forceinline__ float sigmoidf_(float x){ return 1.f/(1.f+expf(-x)); }

__device__ __forceinline__ void ld8f(const float* p, float* f){
  float4 a = *reinterpret_cast<const float4*>(p);
  float4 b = *reinterpret_cast<const float4*>(p+4);
  f[0]=a.x; f[1]=a.y; f[2]=a.z; f[3]=a.w; f[4]=b.x; f[5]=b.y; f[6]=b.z; f[7]=b.w;
}
__device__ __forceinline__ short f2bs(float x){
  union { bf16 h; short s; } u; u.h = __float2bfloat16(x); return u.s;
}
__device__ __forceinline__ bf16x8v cvt8(const float* p){
  float4 a = *reinterpret_cast<const float4*>(p);
  float4 b = *reinterpret_cast<const float4*>(p+4);
  bf16x8v r;
  r[0]=f2bs(a.x); r[1]=f2bs(a.y); r[2]=f2bs(a.z); r[3]=f2bs(a.w);
  r[4]=f2bs(b.x); r[5]=f2bs(b.y); r[6]=f2bs(b.z); r[7]=f2bs(b.w);
  return r;
}

// ---- one-time: enc_proj[s][a] = enc[s]·Wa_enc[a]  (grid 64 x 128 thr) ----
__global__ void k_encproj(const float* __restrict__ enc, const float* __restrict__ Wa_enc,
                          float* __restrict__ ep){
  __shared__ float eL[16][ENCD];
  int s0 = blockIdx.x*16, tid = threadIdx.x;
  #pragma unroll
  for (int i=0;i<16;i++){
    int li = tid + i*128;                      // 2048 float4s
    int t = li>>7, k4 = li&127;
    *reinterpret_cast<float4*>(&eL[t][k4*4]) =
      *reinterpret_cast<const float4*>(enc + (size_t)(s0+t)*ENCD + k4*4);
  }
  __syncthreads();
  const float* w = Wa_enc + (size_t)tid*ENCD;
  float acc[16];
  #pragma unroll
  for (int t=0;t<16;t++) acc[t]=0.f;
  for (int k4=0;k4<128;k4++){
    float4 wv = *reinterpret_cast<const float4*>(w + k4*4);
    #pragma unroll
    for (int t=0;t<16;t++){
      float4 e4 = *reinterpret_cast<const float4*>(&eL[t][k4*4]);
      acc[t] += wv.x*e4.x + wv.y*e4.y + wv.z*e4.z + wv.w*e4.w;
    }
  }
  #pragma unroll
  for (int t=0;t<16;t++) ep[(size_t)(s0+t)*ATTN + tid] = acc[t];
}

// ---- one-time: transpose Wa_h (128x1024) -> WahT (1024x128) ----
__global__ void k_waht(const float* __restrict__ Wa_h, float* __restrict__ WahT){
  int idx = blockIdx.x*256 + threadIdx.x;       // 131072 total
  int j = idx >> 7, a = idx & 127;
  WahT[idx] = Wa_h[(size_t)a*HID + j];
}

// ---- one-time: G[t][r] = b_ih[r]+b_hh[r] + W_ih[r][0:512]·emb(prev_tok(t)) ----
// grid (16 rblk, 32 tblk) x 256 thr
__global__ void k_gbase(const int* __restrict__ sos, const int* __restrict__ tgt,
                        const float* __restrict__ embt, const float* __restrict__ W_ih,
                        const float* __restrict__ b_ih, const float* __restrict__ b_hh,
                        float* __restrict__ G){
  __shared__ float eL[16][EMBED];
  int tid = threadIdx.x;
  int t0 = blockIdx.y*16;
  #pragma unroll
  for (int i=0;i<8;i++){
    int li = tid + i*256;                      // 2048 float4s
    int t = li>>7, k4 = li&127;
    int tg = t0 + t;
    int tok = (tg==0) ? sos[0] : tgt[tg-1];
    *reinterpret_cast<float4*>(&eL[t][k4*4]) =
      *reinterpret_cast<const float4*>(embt + (size_t)tok*EMBED + k4*4);
  }
  __syncthreads();
  int r = blockIdx.x*256 + tid;
  const float* w = W_ih + (size_t)r*(EMBED+ENCD);
  float base = b_ih[r] + b_hh[r];
  float acc[16];
  #pragma unroll
  for (int t=0;t<16;t++) acc[t]=0.f;
  for (int k4=0;k4<128;k4++){
    float4 wv = *reinterpret_cast<const float4*>(w + k4*4);
    #pragma unroll
    for (int t=0;t<16;t++){
      float4 e4 = *reinterpret_cast<const float4*>(&eL[t][k4*4]);
      acc[t] += wv.x*e4.x + wv.y*e4.y + wv.z*e4.z + wv.w*e4.w;
    }
  }
  #pragma unroll
  for (int t=0;t<16;t++) G[(size_t)(t0+t)*4096 + r] = acc[t] + base;
}

// ---- one-time: h/c init + wah partials for step 0 (grid 128 x 128 thr) ----
__global__ void k_init(const float* __restrict__ h0, const float* __restrict__ c0,
                       const float* __restrict__ WahT, float* __restrict__ Hh,
                       float* __restrict__ Cc, float* __restrict__ wahp){
  __shared__ float hl[8];
  int b = blockIdx.x, tid = threadIdx.x;
  if (b < 8){
    int j = b*128 + tid;
    Hh[j] = h0[j];
    Cc[j] = c0[j];
  }
  if (tid < 8) hl[tid] = h0[b*8 + tid];
  __syncthreads();
  float a = 0.f;
  #pragma unroll
  for (int q=0;q<8;q++) a += hl[q]*WahT[(size_t)(b*8+q)*ATTN + tid];
  wahp[b*ATTN + tid] = a;
}

// ---- per step: scores + exp + ctx partials (grid 32 x 256 thr) ----
__global__ void k_attn(int t, const float* __restrict__ enc_proj, const float* __restrict__ enc,
                       const float* __restrict__ v_a, const float* __restrict__ wahp,
                       float* __restrict__ P, float* __restrict__ ctxp, float* __restrict__ denp){
  __shared__ float wp2[2][ATTN];
  __shared__ float wah[ATTN];
  __shared__ float va[ATTN];
  __shared__ float pl[32];
  int b = blockIdx.x, tid = threadIdx.x;
  {   // parallel reduce of the 128 wah partials (all threads)
    int a = tid & 127, hh = tid >> 7;
    float acc = 0.f;
    #pragma unroll 8
    for (int p=0;p<64;p++) acc += wahp[(hh*64+p)*ATTN + a];
    wp2[hh][a] = acc;
  }
  __syncthreads();
  if (tid < ATTN){ wah[tid] = wp2[0][tid] + wp2[1][tid]; va[tid] = v_a[tid]; }
  __syncthreads();
  int row = tid>>3, q = tid&7;
  int s = b*32 + row;
  const float* ep = enc_proj + (size_t)s*ATTN + q*16;
  float sc = 0.f;
  #pragma unroll
  for (int i4=0;i4<4;i4++){
    float4 e4 = *reinterpret_cast<const float4*>(ep + i4*4);
    int a = q*16 + i4*4;
    sc += va[a  ]*tanhf(e4.x + wah[a  ]);
    sc += va[a+1]*tanhf(e4.y + wah[a+1]);
    sc += va[a+2]*tanhf(e4.z + wah[a+2]);
    sc += va[a+3]*tanhf(e4.w + wah[a+3]);
  }
  sc += __shfl_xor(sc,1); sc += __shfl_xor(sc,2); sc += __shfl_xor(sc,4);
  float pv = expf(sc);                      // scores are O(+-5): safe in f32, ratios exact
  if (q==0){ pl[row] = pv; P[(size_t)t*SRC + s] = pv; }
  __syncthreads();
  int d2 = tid*2;
  float c0=0.f, c1=0.f;
  #pragma unroll 8
  for (int s2=0; s2<32; s2++){
    float p = pl[s2];
    float2 e = *reinterpret_cast<const float2*>(enc + (size_t)(b*32+s2)*ENCD + d2);
    c0 += p*e.x; c1 += p*e.y;
  }
  ctxp[b*ENCD + d2] = c0; ctxp[b*ENCD + d2 + 1] = c1;
  if (tid==0){
    float dsum=0.f;
    #pragma unroll
    for (int s2=0;s2<32;s2++) dsum += pl[s2];
    denp[b] = dsum;
  }
}

// ---- per step: reduce ctx, gates, LSTM pointwise, next wah partials (grid 128 x 256) ----
__global__ void k_step(int t, const float* __restrict__ ctxp, const float* __restrict__ denp,
                       const float* __restrict__ W_hh, const float* __restrict__ W_ih,
                       const float* __restrict__ G, float* __restrict__ Hh, float* __restrict__ Cc,
                       const float* __restrict__ WahT, float* __restrict__ wahp,
                       float* __restrict__ invden){
  __shared__ float hs[HID];
  __shared__ float cs[ENCD];
  __shared__ float gl[32];
  __shared__ float hnl[8];
  int b = blockIdx.x, tid = threadIdx.x;
  const float* hprev = Hh + (size_t)t*HID;
  for (int i=tid; i<HID; i+=256) hs[i] = hprev[i];
  float den = 0.f;
  #pragma unroll
  for (int p=0;p<32;p++) den += denp[p];
  float inv = 1.f/den;
  int d2 = tid*2;
  float c0=0.f, c1=0.f;
  #pragma unroll
  for (int p=0;p<32;p++){
    float2 v = *reinterpret_cast<const float2*>(ctxp + p*ENCD + d2);
    c0 += v.x; c1 += v.y;
  }
  cs[d2]   = c0*inv;
  cs[d2+1] = c1*inv;
  if (b==0 && tid==0) invden[t] = inv;
  __syncthreads();
  // 32 gate rows per block: l = gate*8+jj, 8 threads per row (q)
  int l = tid>>3, q = tid&7;
  int gate = l>>3, jj = l&7;
  int j = b*8 + jj;
  int r = gate*HID + j;
  const float* wh = W_hh + (size_t)r*HID;
  const float* wc = W_ih + (size_t)r*(EMBED+ENCD) + EMBED;
  float acc = 0.f;
  float f[8];
  #pragma unroll
  for (int i=0;i<16;i++){
    int k = q*8 + i*64;
    ld8f(wh + k, f);
    float4 h4a = *reinterpret_cast<const float4*>(&hs[k]);
    float4 h4b = *reinterpret_cast<const float4*>(&hs[k+4]);
    acc += f[0]*h4a.x + f[1]*h4a.y + f[2]*h4a.z + f[3]*h4a.w
         + f[4]*h4b.x + f[5]*h4b.y + f[6]*h4b.z + f[7]*h4b.w;
  }
  #pragma unroll
  for (int i=0;i<8;i++){
    int k = q*8 + i*64;
    ld8f(wc + k, f);
    float4 c4a = *reinterpret_cast<const float4*>(&cs[k]);
    float4 c4b = *reinterpret_cast<const float4*>(&cs[k+4]);
    acc += f[0]*c4a.x + f[1]*c4a.y + f[2]*c4a.z + f[3]*c4a.w
         + f[4]*c4b.x + f[5]*c4b.y + f[6]*c4b.z + f[7]*c4b.w;
  }
  acc += __shfl_xor(acc,1); acc += __shfl_xor(acc,2); acc += __shfl_xor(acc,4);
  if (q==0) gl[l] = acc + G[(size_t)t*4096 + r];
  __syncthreads();
  if (tid < 8){
    int jl = b*8 + tid;
    float gi = gl[tid], gf = gl[8+tid], gg = gl[16+tid], go = gl[24+tid];
    float cn = sigmoidf_(gf)*Cc[jl] + sigmoidf_(gi)*tanhf(gg);
    float hn = sigmoidf_(go)*tanhf(cn);
    Cc[jl] = cn;
    Hh[(size_t)(t+1)*HID + jl] = hn;
    hnl[tid] = hn;
  }
  __syncthreads();
  if (tid < ATTN){                         // wah partials for next step (local h slice)
    float a = 0.f;
    #pragma unroll
    for (int qq=0;qq<8;qq++) a += hnl[qq]*WahT[(size_t)(b*8+qq)*ATTN + tid];
    wahp[b*ATTN + tid] = a;
  }
}

// ---- epilogue: logits = H @ W_out^T + b_out (bf16 MFMA, f32 in, f32 out) ----
__global__ __launch_bounds__(256) void k_gemm(const float* __restrict__ A, const float* __restrict__ B,
                                              const float* __restrict__ bias, float* __restrict__ C){
  int bn = blockIdx.x, bm = blockIdx.y;
  int tid = threadIdx.x;
  int wid = tid>>6, lane = tid&63;
  int wr = wid>>1, wc = wid&1;
  int rowf = lane&15, kg = lane>>4;
  const int m_base = bm*128 + wr*64;
  const int n_base = bn*128 + wc*64;
  const float* Ap = A + (size_t)(m_base + rowf)*HID + kg*8;
  const float* Bp = B + (size_t)(n_base + rowf)*HID + kg*8;
  f32x4 acc[4][4];
  #pragma unroll
  for (int i=0;i<4;i++)
    #pragma unroll
    for (int jv=0;jv<4;jv++) acc[i][jv] = (f32x4){0.f,0.f,0.f,0.f};
  for (int kk=0; kk<HID; kk+=32){
    bf16x8v av[4], bv[4];
    #pragma unroll
    for (int mt=0;mt<4;mt++) av[mt] = cvt8(Ap + (size_t)mt*16*HID + kk);
    #pragma unroll
    for (int nt=0;nt<4;nt++) bv[nt] = cvt8(Bp + (size_t)nt*16*HID + kk);
    #pragma unroll
    for (int mt=0;mt<4;mt++)
      #pragma unroll
      for (int nt=0;nt<4;nt++)
        acc[mt][nt] = __builtin_amdgcn_mfma_f32_16x16x32_bf16(av[mt], bv[nt], acc[mt][nt], 0,0,0);
  }
  #pragma unroll
  for (int mt=0;mt<4;mt++){
    #pragma unroll
    for (int nt=0;nt<4;nt++){
      int n = n_base + nt*16 + rowf;
      float bo = bias[n];
      #pragma unroll
      for (int i=0;i<4;i++){
        int m = m_base + mt*16 + kg*4 + i;
        C[(size_t)m*VOCAB + n] = acc[mt][nt][i] + bo;
      }
    }
  }
}

// ---- epilogue: attn = P * invden (f32 out) ----
__global__ void k_attnorm(const float* __restrict__ P, const float* __restrict__ invden,
                          float* __restrict__ out){
  int idx = blockIdx.x*256 + threadIdx.x;
  out[idx] = P[idx]*invden[idx>>10];
}

extern "C" void kernel_launch(void* const* d_in, const int* in_sizes, int n_in,
                              void* d_out, int out_size, void* d_ws, size_t ws_size,
                              hipStream_t stream){
  const float* enc    = (const float*)d_in[0];
  const float* h0     = (const float*)d_in[1];
  const float* c0     = (const float*)d_in[2];
  const int*   sos    = (const int*)d_in[3];
  const int*   tgt    = (const int*)d_in[4];
  const float* embt   = (const float*)d_in[5];
  const float* Wa_enc = (const float*)d_in[6];
  const float* Wa_h   = (const float*)d_in[7];
  const float* v_a    = (const float*)d_in[8];
  const float* W_ih   = (const float*)d_in[9];
  const float* W_hh   = (const float*)d_in[10];
  const float* b_ih   = (const float*)d_in[11];
  const float* b_hh   = (const float*)d_in[12];
  const float* W_out  = (const float*)d_in[13];
  const float* b_out  = (const float*)d_in[14];

  float* ws    = (float*)d_ws;
  float* encp  = ws + OFF_ENCPROJ;
  float* waht  = ws + OFF_WAHT;
  float* G     = ws + OFF_G;
  float* Hh    = ws + OFF_HH;
  float* Cc    = ws + OFF_CC;
  float* P     = ws + OFF_P;
  float* invd  = ws + OFF_INVDEN;
  float* ctxp  = ws + OFF_CTXP;
  float* denp  = ws + OFF_DENP;
  float* wahp  = ws + OFF_WAHP;

  float* out_logits = (float*)d_out;
  float* out_attn   = out_logits + (size_t)TGT*VOCAB;

  k_encproj<<<64, 128, 0, stream>>>(enc, Wa_enc, encp);
  k_waht   <<<512, 256, 0, stream>>>(Wa_h, waht);
  k_gbase  <<<dim3(16, 32), 256, 0, stream>>>(sos, tgt, embt, W_ih, b_ih, b_hh, G);
  k_init   <<<128, 128, 0, stream>>>(h0, c0, waht, Hh, Cc, wahp);

  for (int t=0; t<TGT; t++){
    k_attn<<<32, 256, 0, stream>>>(t, encp, enc, v_a, wahp, P, ctxp, denp);
    k_step<<<128, 256, 0, stream>>>(t, ctxp, denp, W_hh, W_ih, G, Hh, Cc, waht, wahp, invd);
  }

  k_gemm   <<<dim3(250, 4), 256, 0, stream>>>(Hh + HID, W_out, b_out, out_logits);
  k_attnorm<<<2048, 256, 0, stream>>>(P, invd, out_attn);
}